// Round 5
// baseline (32.307 us; speedup 1.0000x reference)
//
#include <hip/hip_runtime.h>

// MeanPoolingWithoutPadding: features [B,S,D] f32, lengths [B] i32,
// out [B,D] f32 = sum_{s<len[b]} f[b,s,:] / len[b].  B=64, S=2048, D=512.
//
// Two-phase split-S reduction (deterministic, no atomics; R3's fused
// device-scope-fence version was a 13x regression).
//   pool_partial: grid (B, nsplit=64), 128 thr. Per-b chunk c=ceil(len/64);
//     split k sums rows [k*c, min((k+1)*c, len)) -> ws[b][k][:]. Splits with
//     k*c >= len write NOTHING (final never reads them).
//   pool_final: grid (B, 4), 128 thr — 256 blocks so ALL CUs participate
//     (R2-R4's 64-block final was 1/4-device BW-bound, ~5 us). Each block
//     owns a 128-column slice; 4 groups of 32 lanes stride the nact splits,
//     LDS combine, divide by len, store.

#define DDIM 512
#define TPB  128
#define NSPLIT_MAX 64

__device__ __forceinline__ void acc4(float4& a, const float4& v) {
    a.x += v.x; a.y += v.y; a.z += v.z; a.w += v.w;
}

__global__ void __launch_bounds__(TPB)
pool_partial(const float* __restrict__ feat, const int* __restrict__ lengths,
             float* __restrict__ ws, int S, int nsplit) {
    const int b     = blockIdx.x;
    const int split = blockIdx.y;
    const int tid   = threadIdx.x;
    const int len   = lengths[b];

    const int chunk = (len + nsplit - 1) / nsplit;  // per-b balanced
    const int s0 = split * chunk;
    if (s0 >= len) return;                          // inactive split: no write
    const int s1 = min(s0 + chunk, len);

    float4 a0 = {0.f, 0.f, 0.f, 0.f};
    float4 a1 = {0.f, 0.f, 0.f, 0.f};
    float4 a2 = {0.f, 0.f, 0.f, 0.f};
    float4 a3 = {0.f, 0.f, 0.f, 0.f};

    const float4* __restrict__ base =
        reinterpret_cast<const float4*>(feat + (size_t)b * S * DDIM) + tid;
    const int ld4 = DDIM / 4;

    int s = s0;
    for (; s + 7 < s1; s += 8) {
        float4 v0 = base[(size_t)(s + 0) * ld4];
        float4 v1 = base[(size_t)(s + 1) * ld4];
        float4 v2 = base[(size_t)(s + 2) * ld4];
        float4 v3 = base[(size_t)(s + 3) * ld4];
        float4 v4 = base[(size_t)(s + 4) * ld4];
        float4 v5 = base[(size_t)(s + 5) * ld4];
        float4 v6 = base[(size_t)(s + 6) * ld4];
        float4 v7 = base[(size_t)(s + 7) * ld4];
        acc4(a0, v0); acc4(a1, v1); acc4(a2, v2); acc4(a3, v3);
        acc4(a0, v4); acc4(a1, v5); acc4(a2, v6); acc4(a3, v7);
    }
    for (; s < s1; ++s) {
        float4 v = base[(size_t)s * ld4];
        acc4(a0, v);
    }
    acc4(a0, a1); acc4(a2, a3); acc4(a0, a2);

    float4* wsp = reinterpret_cast<float4*>(ws + ((size_t)b * nsplit + split) * DDIM) + tid;
    *wsp = a0;
}

// grid (B, 4), 128 threads. Block (b,dq) owns float4 columns [dq*32, dq*32+32).
__global__ void __launch_bounds__(TPB)
pool_final(const float* __restrict__ ws, const int* __restrict__ lengths,
           float* __restrict__ out, int nsplit) {
    const int b    = blockIdx.x;
    const int dq   = blockIdx.y;
    const int tid  = threadIdx.x;
    const int grp  = tid >> 5;          // 0..3
    const int lane = tid & 31;
    const int f4   = dq * 32 + lane;    // 0..127 float4 column index

    const int len   = lengths[b];
    const int chunk = (len + nsplit - 1) / nsplit;
    const int nact  = (len + chunk - 1) / chunk;    // splits actually written

    const float4* __restrict__ wsp =
        reinterpret_cast<const float4*>(ws + (size_t)b * nsplit * DDIM) + f4;
    const int ld4 = DDIM / 4;

    float4 acc0 = {0.f, 0.f, 0.f, 0.f};
    float4 acc1 = {0.f, 0.f, 0.f, 0.f};
    int p = grp;
    for (; p + 4 < nact; p += 8) {
        float4 w0 = wsp[(size_t)p * ld4];
        float4 w1 = wsp[(size_t)(p + 4) * ld4];
        acc4(acc0, w0); acc4(acc1, w1);
    }
    for (; p < nact; p += 4) acc4(acc0, wsp[(size_t)p * ld4]);
    acc4(acc0, acc1);

    __shared__ float4 red[3][32];
    if (grp > 0) red[grp - 1][lane] = acc0;
    __syncthreads();
    if (grp == 0) {
        acc4(acc0, red[0][lane]);
        acc4(acc0, red[1][lane]);
        acc4(acc0, red[2][lane]);
        const float inv = 1.0f / (float)len;
        float4 r = {acc0.x * inv, acc0.y * inv, acc0.z * inv, acc0.w * inv};
        reinterpret_cast<float4*>(out + (size_t)b * DDIM)[f4] = r;
    }
}

// Fallback (too-small workspace): one block per b, full S loop.
__global__ void __launch_bounds__(TPB)
pool_direct(const float* __restrict__ feat, const int* __restrict__ lengths,
            float* __restrict__ out, int S) {
    const int b   = blockIdx.x;
    const int tid = threadIdx.x;
    const int len = lengths[b];
    float4 a0 = {0.f, 0.f, 0.f, 0.f};
    float4 a1 = {0.f, 0.f, 0.f, 0.f};
    float4 a2 = {0.f, 0.f, 0.f, 0.f};
    float4 a3 = {0.f, 0.f, 0.f, 0.f};
    const float4* __restrict__ base =
        reinterpret_cast<const float4*>(feat + (size_t)b * S * DDIM) + tid;
    const int ld4 = DDIM / 4;
    int s = 0;
    for (; s + 3 < len; s += 4) {
        float4 v0 = base[(size_t)(s + 0) * ld4];
        float4 v1 = base[(size_t)(s + 1) * ld4];
        float4 v2 = base[(size_t)(s + 2) * ld4];
        float4 v3 = base[(size_t)(s + 3) * ld4];
        acc4(a0, v0); acc4(a1, v1); acc4(a2, v2); acc4(a3, v3);
    }
    for (; s < len; ++s) { float4 v = base[(size_t)s * ld4]; acc4(a0, v); }
    acc4(a0, a1); acc4(a2, a3); acc4(a0, a2);
    const float inv = 1.0f / (float)len;
    float4 r = {a0.x * inv, a0.y * inv, a0.z * inv, a0.w * inv};
    reinterpret_cast<float4*>(out + (size_t)b * DDIM)[tid] = r;
}

extern "C" void kernel_launch(void* const* d_in, const int* in_sizes, int n_in,
                              void* d_out, int out_size, void* d_ws, size_t ws_size,
                              hipStream_t stream) {
    const float* feat    = (const float*)d_in[0];
    const int*   lengths = (const int*)d_in[1];
    float*       out     = (float*)d_out;

    const int B = in_sizes[1];                       // 64
    const int S = in_sizes[0] / (B * DDIM);          // 2048

    const size_t per_split = (size_t)B * DDIM * sizeof(float);
    int nsplit = (int)(ws_size / per_split);
    if (nsplit > NSPLIT_MAX) nsplit = NSPLIT_MAX;

    if (nsplit >= 4) {
        float* ws = (float*)d_ws;
        dim3 grid1(B, nsplit);
        dim3 grid2(B, 4);
        pool_partial<<<grid1, TPB, 0, stream>>>(feat, lengths, ws, S, nsplit);
        pool_final<<<grid2, TPB, 0, stream>>>(ws, lengths, out, nsplit);
    } else {
        pool_direct<<<B, TPB, 0, stream>>>(feat, lengths, out, S);
    }
}

// Round 6
// 31.430 us; speedup vs baseline: 1.0279x; 1.0279x over previous
//
#include <hip/hip_runtime.h>

// MeanPoolingWithoutPadding: features [B,S,D] f32, lengths [B] i32,
// out [B,D] f32 = sum_{s<len[b]} f[b,s,:] / len[b].  B=64, S=2048, D=512.
//
// Two-phase split-S reduction (deterministic, no atomics).
//   pool_partial: 4096 blocks x 128 thr. Work unit u in [0,4096) maps to
//     (b = u&63, split = u>>6). Block id -> u via the NON-LINEAR bijection
//     u = id ^ (id>>6): hardware hands CU j ids with a fixed stride that is
//     a multiple of 64, so with the identity map b = id%64 is CONSTANT per
//     CU -> a CU owning only len~2048 samples does ~2x average bytes (the
//     R2-R5 ~30 us plateau, ~40% over the 21 us HBM floor). The XOR mixes
//     split bits into b so each CU sees varied-length samples.
//   pool_final: grid (B,4) = 256 blocks so all CUs participate; reads only
//     the nact written splits.

#define DDIM 512
#define TPB  128
#define NSPLIT 64

__device__ __forceinline__ void acc4(float4& a, const float4& v) {
    a.x += v.x; a.y += v.y; a.z += v.z; a.w += v.w;
}

__global__ void __launch_bounds__(TPB)
pool_partial(const float* __restrict__ feat, const int* __restrict__ lengths,
             float* __restrict__ ws, int S) {
    const int id  = blockIdx.x;
    const int u   = id ^ (id >> 6);      // bijection on [0, 4096)
    const int b     = u & 63;
    const int split = u >> 6;
    const int tid   = threadIdx.x;
    const int len   = lengths[b];

    const int chunk = (len + NSPLIT - 1) / NSPLIT;  // per-b balanced
    const int s0 = split * chunk;
    if (s0 >= len) return;                          // inactive split: no write
    const int s1 = min(s0 + chunk, len);

    float4 a0 = {0.f, 0.f, 0.f, 0.f};
    float4 a1 = {0.f, 0.f, 0.f, 0.f};
    float4 a2 = {0.f, 0.f, 0.f, 0.f};
    float4 a3 = {0.f, 0.f, 0.f, 0.f};

    const float4* __restrict__ base =
        reinterpret_cast<const float4*>(feat + (size_t)b * S * DDIM) + tid;
    const int ld4 = DDIM / 4;

    int s = s0;
    for (; s + 7 < s1; s += 8) {
        float4 v0 = base[(size_t)(s + 0) * ld4];
        float4 v1 = base[(size_t)(s + 1) * ld4];
        float4 v2 = base[(size_t)(s + 2) * ld4];
        float4 v3 = base[(size_t)(s + 3) * ld4];
        float4 v4 = base[(size_t)(s + 4) * ld4];
        float4 v5 = base[(size_t)(s + 5) * ld4];
        float4 v6 = base[(size_t)(s + 6) * ld4];
        float4 v7 = base[(size_t)(s + 7) * ld4];
        acc4(a0, v0); acc4(a1, v1); acc4(a2, v2); acc4(a3, v3);
        acc4(a0, v4); acc4(a1, v5); acc4(a2, v6); acc4(a3, v7);
    }
    for (; s < s1; ++s) {
        float4 v = base[(size_t)s * ld4];
        acc4(a0, v);
    }
    acc4(a0, a1); acc4(a2, a3); acc4(a0, a2);

    float4* wsp = reinterpret_cast<float4*>(ws + ((size_t)b * NSPLIT + split) * DDIM) + tid;
    *wsp = a0;
}

// grid (B, 4), 128 threads. Block (b,dq) owns float4 columns [dq*32, dq*32+32).
__global__ void __launch_bounds__(TPB)
pool_final(const float* __restrict__ ws, const int* __restrict__ lengths,
           float* __restrict__ out) {
    const int b    = blockIdx.x;
    const int dq   = blockIdx.y;
    const int tid  = threadIdx.x;
    const int grp  = tid >> 5;          // 0..3
    const int lane = tid & 31;
    const int f4   = dq * 32 + lane;    // float4 column index

    const int len   = lengths[b];
    const int chunk = (len + NSPLIT - 1) / NSPLIT;
    const int nact  = (len + chunk - 1) / chunk;    // splits actually written

    const float4* __restrict__ wsp =
        reinterpret_cast<const float4*>(ws + (size_t)b * NSPLIT * DDIM) + f4;
    const int ld4 = DDIM / 4;

    float4 acc0 = {0.f, 0.f, 0.f, 0.f};
    float4 acc1 = {0.f, 0.f, 0.f, 0.f};
    int p = grp;
    for (; p + 4 < nact; p += 8) {
        float4 w0 = wsp[(size_t)p * ld4];
        float4 w1 = wsp[(size_t)(p + 4) * ld4];
        acc4(acc0, w0); acc4(acc1, w1);
    }
    for (; p < nact; p += 4) acc4(acc0, wsp[(size_t)p * ld4]);
    acc4(acc0, acc1);

    __shared__ float4 red[3][32];
    if (grp > 0) red[grp - 1][lane] = acc0;
    __syncthreads();
    if (grp == 0) {
        acc4(acc0, red[0][lane]);
        acc4(acc0, red[1][lane]);
        acc4(acc0, red[2][lane]);
        const float inv = 1.0f / (float)len;
        float4 r = {acc0.x * inv, acc0.y * inv, acc0.z * inv, acc0.w * inv};
        reinterpret_cast<float4*>(out + (size_t)b * DDIM)[f4] = r;
    }
}

// Fallback (too-small workspace): one block per b, full S loop.
__global__ void __launch_bounds__(TPB)
pool_direct(const float* __restrict__ feat, const int* __restrict__ lengths,
            float* __restrict__ out, int S) {
    const int b   = blockIdx.x;
    const int tid = threadIdx.x;
    const int len = lengths[b];
    float4 a0 = {0.f, 0.f, 0.f, 0.f};
    float4 a1 = {0.f, 0.f, 0.f, 0.f};
    float4 a2 = {0.f, 0.f, 0.f, 0.f};
    float4 a3 = {0.f, 0.f, 0.f, 0.f};
    const float4* __restrict__ base =
        reinterpret_cast<const float4*>(feat + (size_t)b * S * DDIM) + tid;
    const int ld4 = DDIM / 4;
    int s = 0;
    for (; s + 3 < len; s += 4) {
        float4 v0 = base[(size_t)(s + 0) * ld4];
        float4 v1 = base[(size_t)(s + 1) * ld4];
        float4 v2 = base[(size_t)(s + 2) * ld4];
        float4 v3 = base[(size_t)(s + 3) * ld4];
        acc4(a0, v0); acc4(a1, v1); acc4(a2, v2); acc4(a3, v3);
    }
    for (; s < len; ++s) { float4 v = base[(size_t)s * ld4]; acc4(a0, v); }
    acc4(a0, a1); acc4(a2, a3); acc4(a0, a2);
    const float inv = 1.0f / (float)len;
    float4 r = {a0.x * inv, a0.y * inv, a0.z * inv, a0.w * inv};
    reinterpret_cast<float4*>(out + (size_t)b * DDIM)[tid] = r;
}

extern "C" void kernel_launch(void* const* d_in, const int* in_sizes, int n_in,
                              void* d_out, int out_size, void* d_ws, size_t ws_size,
                              hipStream_t stream) {
    const float* feat    = (const float*)d_in[0];
    const int*   lengths = (const int*)d_in[1];
    float*       out     = (float*)d_out;

    const int B = in_sizes[1];                       // 64
    const int S = in_sizes[0] / (B * DDIM);          // 2048

    const size_t need = (size_t)B * NSPLIT * DDIM * sizeof(float);

    if (ws_size >= need && B == 64) {
        float* ws = (float*)d_ws;
        dim3 grid2(B, 4);
        pool_partial<<<B * NSPLIT, TPB, 0, stream>>>(feat, lengths, ws, S);
        pool_final<<<grid2, TPB, 0, stream>>>(ws, lengths, out);
    } else {
        pool_direct<<<B, TPB, 0, stream>>>(feat, lengths, out, S);
    }
}